// Round 1
// baseline (99.802 us; speedup 1.0000x reference)
//
#include <hip/hip_runtime.h>
#include <hip/hip_bf16.h>

constexpr int HIDDEN = 256;   // per-bag hidden dim
constexpr int BAG    = 32;
constexpr int ROWS   = 4;     // batch rows per block (one per wave)

__global__ __launch_bounds__(256) void nnue_fused(
    const int*   __restrict__ us,
    const int*   __restrict__ them,
    const float* __restrict__ emb,
    const float* __restrict__ w1, const float* __restrict__ b1,
    const float* __restrict__ w2, const float* __restrict__ b2,
    const float* __restrict__ w3, const float* __restrict__ b3,
    float*       __restrict__ out)
{
    __shared__ float x_lds[ROWS][2 * HIDDEN];   // concat(acc_us, acc_them)
    __shared__ float y1_lds[ROWS][32];
    __shared__ float y2_lds[ROWS][32];

    const int tid  = threadIdx.x;
    const int wave = tid >> 6;          // 0..3
    const int lane = tid & 63;
    const int row  = blockIdx.x * ROWS + wave;

    // ---------- gather / bag-sum: one wave per row; lane l owns elems 4l..4l+3
    int myidx;
    {
        const int* up = us   + (size_t)row * BAG;
        const int* tp = them + (size_t)row * BAG;
        myidx = (lane < BAG) ? up[lane] : tp[lane - BAG];
    }
    const float4* emb4 = reinterpret_cast<const float4*>(emb);
    float4 accU = make_float4(0.f, 0.f, 0.f, 0.f);
    float4 accT = make_float4(0.f, 0.f, 0.f, 0.f);
#pragma unroll
    for (int i = 0; i < BAG; ++i) {
        const int iu = __shfl(myidx, i);
        const int it = __shfl(myidx, BAG + i);
        // emb[PAD_IDX] is all zeros, so no masking needed — adding it is exact.
        const float4 vu = emb4[(size_t)iu * (HIDDEN / 4) + lane];
        const float4 vt = emb4[(size_t)it * (HIDDEN / 4) + lane];
        accU.x += vu.x; accU.y += vu.y; accU.z += vu.z; accU.w += vu.w;
        accT.x += vt.x; accT.y += vt.y; accT.z += vt.z; accT.w += vt.w;
    }
    {
        float4* xv = reinterpret_cast<float4*>(&x_lds[wave][0]);
        xv[lane]      = accU;  // elems 0..255   (acc_us)
        xv[64 + lane] = accT;  // elems 256..511 (acc_them)
    }
    __syncthreads();

    // ---------- fc1: 512 -> 32, clip(0,1). Two threads per (row, j): k halves.
    {
        const int r    = tid >> 6;      // row within block
        const int sub  = tid & 63;
        const int j    = sub >> 1;      // output 0..31
        const int half = sub & 1;       // k-half
        const float4* xr = reinterpret_cast<const float4*>(&x_lds[r][0]) + half * 64;
        const float4* wr = reinterpret_cast<const float4*>(w1 + (size_t)j * (2 * HIDDEN)) + half * 64;
        float s = 0.f;
#pragma unroll 8
        for (int k = 0; k < 64; ++k) {
            const float4 xk = xr[k];
            const float4 wk = wr[k];
            s += xk.x * wk.x + xk.y * wk.y + xk.z * wk.z + xk.w * wk.w;
        }
        s += __shfl_xor(s, 1);
        if (half == 0) {
            s += b1[j];
            y1_lds[r][j] = fminf(fmaxf(s, 0.f), 1.f);
        }
    }
    __syncthreads();

    // ---------- fc2: 32 -> 32, clip(0,1)
    if (tid < ROWS * 32) {
        const int r = tid >> 5;
        const int j = tid & 31;
        const float* wr = w2 + j * 32;
        float s = b2[j];
#pragma unroll
        for (int k = 0; k < 32; ++k) s += y1_lds[r][k] * wr[k];
        y2_lds[r][j] = fminf(fmaxf(s, 0.f), 1.f);
    }
    __syncthreads();

    // ---------- fc3: 32 -> 1, tanh
    if (tid < ROWS) {
        const int r = tid;
        float s = b3[0];
#pragma unroll
        for (int k = 0; k < 32; ++k) s += y2_lds[r][k] * w3[k];
        out[blockIdx.x * ROWS + r] = tanhf(s);
    }
}

extern "C" void kernel_launch(void* const* d_in, const int* in_sizes, int n_in,
                              void* d_out, int out_size, void* d_ws, size_t ws_size,
                              hipStream_t stream) {
    const int*   us   = (const int*)  d_in[0];
    const int*   them = (const int*)  d_in[1];
    const float* emb  = (const float*)d_in[2];
    const float* w1   = (const float*)d_in[3];
    const float* b1   = (const float*)d_in[4];
    const float* w2   = (const float*)d_in[5];
    const float* b2   = (const float*)d_in[6];
    const float* w3   = (const float*)d_in[7];
    const float* b3   = (const float*)d_in[8];
    float* out = (float*)d_out;

    const int batch = in_sizes[0] / BAG;          // 8192
    const int grid  = (batch + ROWS - 1) / ROWS;  // 2048 blocks
    nnue_fused<<<grid, 256, 0, stream>>>(us, them, emb,
                                         w1, b1, w2, b2, w3, b3, out);
}